// Round 15
// baseline (389.677 us; speedup 1.0000x reference)
//
#include <hip/hip_runtime.h>
#include <hip/hip_bf16.h>
#include <cstdint>

// Problem constants
static constexpr int Bc  = 4;
static constexpr int Sc  = 8192;
static constexpr int Dc  = 1024;
static constexpr int Hc  = 16;
static constexpr int BHc = Bc * Hc;   // 64
static constexpr int Mc  = Bc * Sc;   // 32768
static constexpr int N3c = 3 * Dc;    // 3072
static constexpr float EPSc = 1e-6f;

using bf16x8 = __attribute__((ext_vector_type(8))) __bf16;
using f32x4  = __attribute__((ext_vector_type(4))) float;

__device__ __forceinline__ ushort f2bf(float f) {
  union { float f; uint32_t u; } v; v.f = f;
  uint32_t u = v.u;
  return (ushort)((u + 0x7fffu + ((u >> 16) & 1u)) >> 16);  // RNE
}
__device__ __forceinline__ float bf2f(ushort h) {
  union { uint32_t u; float f; } v; v.u = ((uint32_t)h) << 16;
  return v.f;
}

typedef const __attribute__((address_space(1))) unsigned int* gas_u32p;
typedef __attribute__((address_space(3))) unsigned int* las_u32p;
__device__ __forceinline__ void gld_lds16(const void* g, void* l) {
  __builtin_amdgcn_global_load_lds((gas_u32p)g, (las_u32p)l, 16, 0, 0);
}

// ---------------------------------------------------------------- kernel 0: fused prep
__global__ __launch_bounds__(256) void prep_k(const float* __restrict__ x,
                                              ushort* __restrict__ xb,
                                              const float* __restrict__ Wq,
                                              const float* __restrict__ Wp,
                                              const float* __restrict__ bq,
                                              const float* __restrict__ bp,
                                              ushort* __restrict__ W3b,
                                              float* __restrict__ bias3) {
  const int t = threadIdx.x;
  if (blockIdx.x < 2048) {
    const int n4 = Mc * Dc / 4;
    for (int i = blockIdx.x * 256 + t; i < n4; i += 2048 * 256) {
      float4 v = reinterpret_cast<const float4*>(x)[i];
      ushort4 o; o.x = f2bf(v.x); o.y = f2bf(v.y); o.z = f2bf(v.z); o.w = f2bf(v.w);
      reinterpret_cast<ushort4*>(xb)[i] = o;
    }
    return;
  }
  const int bx = blockIdx.x - 2048;   // 0..47
  const int p = bx >> 4, h = bx & 15;
  if (p == 2) {
    const int base = 2048 + h * 64;
    for (int li = t; li < 64 * 256; li += 256) {
      int r = li >> 8, c4 = (li & 255) * 4;
      float4 v = *reinterpret_cast<const float4*>(&Wq[(size_t)(base + r) * 1024 + c4]);
      ushort4 o; o.x = f2bf(v.x); o.y = f2bf(v.y); o.z = f2bf(v.z); o.w = f2bf(v.w);
      *reinterpret_cast<ushort4*>(&W3b[(size_t)(base + r) * 1024 + c4]) = o;
    }
    if (t < 64) bias3[base + t] = bq[base + t];
    return;
  }
  __shared__ ushort Ws[64 * 64];    // [a][hd]
  __shared__ ushort Tq[256 * 64];   // [d][hd]
  const int rbase = p * 1024 + h * 64;
  for (int li = t; li < 64 * 16; li += 256) {
    int a = li >> 4, h4 = (li & 15) * 4;
    float4 v = *reinterpret_cast<const float4*>(&Wp[a * 64 + h4]);
    ushort4 o; o.x = f2bf(v.x); o.y = f2bf(v.y); o.z = f2bf(v.z); o.w = f2bf(v.w);
    *reinterpret_cast<ushort4*>(&Ws[a * 64 + h4]) = o;
  }
  if (t < 64) {
    float s = bp[t];
    for (int hd = 0; hd < 64; ++hd) s += Wp[t * 64 + hd] * bq[rbase + hd];
    bias3[rbase + t] = s;
  }
  const int w = t >> 6, lane = t & 63, lr = lane & 15, kg = lane >> 4;
  for (int dt = 0; dt < 4; ++dt) {
    __syncthreads();
    for (int li = t; li < 64 * 64; li += 256) {
      int hd = li >> 6, d4 = (li & 63) * 4;
      float4 v = *reinterpret_cast<const float4*>(&Wq[(size_t)(rbase + hd) * 1024 + dt * 256 + d4]);
      Tq[(d4 + 0) * 64 + hd] = f2bf(v.x);
      Tq[(d4 + 1) * 64 + hd] = f2bf(v.y);
      Tq[(d4 + 2) * 64 + hd] = f2bf(v.z);
      Tq[(d4 + 3) * 64 + hd] = f2bf(v.w);
    }
    __syncthreads();
    f32x4 acc[4][4];
#pragma unroll
    for (int i = 0; i < 4; i++)
#pragma unroll
      for (int j = 0; j < 4; j++) acc[i][j] = (f32x4){0.f, 0.f, 0.f, 0.f};
#pragma unroll
    for (int kk = 0; kk < 2; ++kk) {
      bf16x8 af[4], bfr[4];
#pragma unroll
      for (int i = 0; i < 4; i++)
        af[i] = *reinterpret_cast<const bf16x8*>(&Ws[(i * 16 + lr) * 64 + kk * 32 + kg * 8]);
#pragma unroll
      for (int j = 0; j < 4; j++)
        bfr[j] = *reinterpret_cast<const bf16x8*>(&Tq[(w * 64 + j * 16 + lr) * 64 + kk * 32 + kg * 8]);
#pragma unroll
      for (int i = 0; i < 4; i++)
#pragma unroll
        for (int j = 0; j < 4; j++)
          acc[i][j] = __builtin_amdgcn_mfma_f32_16x16x32_bf16(af[i], bfr[j], acc[i][j], 0, 0, 0);
    }
#pragma unroll
    for (int i = 0; i < 4; i++)
#pragma unroll
      for (int j = 0; j < 4; j++)
#pragma unroll
        for (int r = 0; r < 4; r++)
          W3b[(size_t)(rbase + i * 16 + kg * 4 + r) * 1024 + dt * 256 + w * 64 + j * 16 + lr] =
              f2bf(acc[i][j][r]);
  }
}

// ================================================================ shared GEMM machinery
// 256x256 tile, BK=64, 8 waves, 2-dbuf LDS (128 KB), 2 barriers per K-tile, vmcnt(8)
// counted (stage t+1 issued one full COMPUTE before its wait). Swizzle: 8 granules/row,
// store g=(l&7)^((l>>3)&7); read (kk*4+kg)^(lr&7) — same involution pair as ktv_part.

// ---------------------------------------------------------------- kernel 1: K/V GEMM + fused phi(K)
__global__ __launch_bounds__(512, 2) void gemm_kv_k(const ushort* __restrict__ xb,
                                                    const ushort* __restrict__ W3b,
                                                    const float* __restrict__ bias3,
                                                    ushort* __restrict__ KTb,
                                                    ushort* __restrict__ VTb) {
  __shared__ __align__(16) ushort As[2 * 16384];   // 2 bufs x [256 rows][64 k] = 64 KB
  __shared__ __align__(16) ushort Bs[2 * 16384];   // 64 KB
  const int t = threadIdx.x, wave = t >> 6, lane = t & 63;
  const int lr = lane & 15, kg = lane >> 4;
  const int wr = wave >> 2, wc = wave & 3;

  // XCD-bijective swizzle: 1024 = 8 * 128; per XCD 16 m x 8 n, n fastest.
  const int flat = blockIdx.x;
  const int swz  = (flat & 7) * 128 + (flat >> 3);
  const int n0 = 1024 + (swz % 8) * 256;
  const int m0 = (swz / 8) * 256;

  const int srow8 = lane >> 3;                       // row within 8-row instr chunk
  const int sg    = (lane & 7) ^ ((lane >> 3) & 7);  // swizzled global 8-elem col chunk

  auto STAGE = [&](int tile, int buf) {
    const int kt = tile * 64;
#pragma unroll
    for (int i = 0; i < 4; ++i) {
      const int r0 = (wave * 4 + i) * 8;
      gld_lds16(xb  + (size_t)(m0 + r0 + srow8) * 1024 + kt + sg * 8,
                As + buf * 16384 + (wave * 4 + i) * 512);
      gld_lds16(W3b + (size_t)(n0 + r0 + srow8) * 1024 + kt + sg * 8,
                Bs + buf * 16384 + (wave * 4 + i) * 512);
    }
  };

  f32x4 acc[8][4];
#pragma unroll
  for (int f = 0; f < 8; f++)
#pragma unroll
    for (int j = 0; j < 4; j++) acc[f][j] = (f32x4){0.f, 0.f, 0.f, 0.f};

  auto COMPUTE = [&](int buf) {
    const ushort* Ab = As + buf * 16384;
    const ushort* Bb = Bs + buf * 16384;
#pragma unroll
    for (int kk = 0; kk < 2; ++kk) {
      const int cp = ((kk * 4 + kg) ^ (lr & 7)) * 8;
      bf16x8 af[8], bfr[4];
#pragma unroll
      for (int f = 0; f < 8; f++)
        af[f] = *reinterpret_cast<const bf16x8*>(Ab + (wr * 128 + f * 16 + lr) * 64 + cp);
#pragma unroll
      for (int j = 0; j < 4; j++)
        bfr[j] = *reinterpret_cast<const bf16x8*>(Bb + (wc * 64 + j * 16 + lr) * 64 + cp);
      __builtin_amdgcn_s_setprio(1);
#pragma unroll
      for (int f = 0; f < 8; f++)
#pragma unroll
        for (int j = 0; j < 4; j++)
          acc[f][j] = __builtin_amdgcn_mfma_f32_16x16x32_bf16(af[f], bfr[j], acc[f][j], 0, 0, 0);
      __builtin_amdgcn_s_setprio(0);
    }
  };

  // prologue + 16-tile loop: per tile {STAGE(t+1); vmcnt(8); bar; COMPUTE(t); bar}
  STAGE(0, 0);
#pragma unroll 1
  for (int tt = 0; tt < 7; ++tt) {
    STAGE(tt * 2 + 1, 1);
    asm volatile("s_waitcnt vmcnt(8)" ::: "memory");
    __builtin_amdgcn_s_barrier();
    COMPUTE(0);
    asm volatile("" ::: "memory");
    __builtin_amdgcn_s_barrier();
    STAGE(tt * 2 + 2, 0);
    asm volatile("s_waitcnt vmcnt(8)" ::: "memory");
    __builtin_amdgcn_s_barrier();
    COMPUTE(1);
    asm volatile("" ::: "memory");
    __builtin_amdgcn_s_barrier();
  }
  STAGE(15, 1);
  asm volatile("s_waitcnt vmcnt(8)" ::: "memory");
  __builtin_amdgcn_s_barrier();
  COMPUTE(0);
  asm volatile("" ::: "memory");
  __builtin_amdgcn_s_barrier();
  asm volatile("s_waitcnt vmcnt(0)" ::: "memory");
  __builtin_amdgcn_s_barrier();
  COMPUTE(1);

  // epilogue: part 1 = phiK (T), part 2 = V (T)
  const int n0w  = n0 + wc * 64;
  const int part = n0w >> 10;           // 1 or 2
  const int h    = (n0w & 1023) >> 6;
  const int bq   = m0 >> 13;
  const int s_base = (m0 & 8191) + wr * 128;
  float bias[4];
#pragma unroll
  for (int j = 0; j < 4; j++) bias[j] = bias3[n0w + j * 16 + lr];

  ushort* dst = ((part == 1) ? KTb : VTb) + ((size_t)(bq * Hc + h)) * 64 * Sc;
#pragma unroll
  for (int f = 0; f < 8; f++) {
    const int s = s_base + f * 16 + kg * 4;
#pragma unroll
    for (int j = 0; j < 4; j++) {
      ushort4 o;
      if (part == 1) {
#pragma unroll
        for (int r = 0; r < 4; r++) {
          float p = acc[f][j][r] + bias[j];
          (&o.x)[r] = f2bf(sqrtf(1.f + p * p));
        }
      } else {
#pragma unroll
        for (int r = 0; r < 4; r++) (&o.x)[r] = f2bf(acc[f][j][r] + bias[j]);
      }
      *reinterpret_cast<ushort4*>(&dst[(size_t)(j * 16 + lr) * Sc + s]) = o;
    }
  }
}

// ---------------------------------------------------------------- kernel 2: KTV + ksum partials (T-layout inputs)
__global__ __launch_bounds__(256, 2) void ktv_part_k(const ushort* __restrict__ KT,
                                                     const ushort* __restrict__ VT,
                                                     float* __restrict__ KTVp,
                                                     float* __restrict__ ksump) {
  __shared__ __align__(16) ushort Ks[2 * 8192];   // 2 bufs x [64 a][128 s]
  __shared__ __align__(16) ushort Vs[2 * 8192];
  const int t = threadIdx.x, chunk = blockIdx.x, bh = blockIdx.y;
  const int wave = t >> 6, lane = t & 63, lr = lane & 15, kg = lane >> 4;
  const size_t hb = (size_t)bh * 64 * Sc;
  const int s0 = chunk * 1024;

  f32x4 acc[4];
  f32x4 acc_ks;
#pragma unroll
  for (int j = 0; j < 4; j++) acc[j] = (f32x4){0.f, 0.f, 0.f, 0.f};
  acc_ks = (f32x4){0.f, 0.f, 0.f, 0.f};

  bf16x8 ones;
#pragma unroll
  for (int e = 0; e < 8; e++) ones[e] = (__bf16)1.0f;

  const int srl = t >> 4;
  const int scc = (t & 15) ^ ((t >> 4) & 7);
  const int wb  = (t >> 6) * 512;

  auto STG = [&](int st, int buf) {
    const int sb = s0 + st * 128;
#pragma unroll
    for (int is = 0; is < 4; ++is) {
      const int row = is * 16 + srl;
      gld_lds16(KT + hb + (size_t)row * Sc + sb + scc * 8, Ks + buf * 8192 + is * 2048 + wb);
      gld_lds16(VT + hb + (size_t)row * Sc + sb + scc * 8, Vs + buf * 8192 + is * 2048 + wb);
    }
  };

  auto COMPUTE = [&](int buf) {
    const ushort* Kb = Ks + buf * 8192;
    const ushort* Vb = Vs + buf * 8192;
#pragma unroll
    for (int ks4 = 0; ks4 < 4; ++ks4) {
      const int pos = ((ks4 * 4 + kg) ^ (lr & 7)) * 8;
      bf16x8 af = *reinterpret_cast<const bf16x8*>(Kb + (wave * 16 + lr) * 128 + pos);
      acc_ks = __builtin_amdgcn_mfma_f32_16x16x32_bf16(af, ones, acc_ks, 0, 0, 0);
#pragma unroll
      for (int j = 0; j < 4; ++j) {
        bf16x8 bv = *reinterpret_cast<const bf16x8*>(Vb + (j * 16 + lr) * 128 + pos);
        acc[j] = __builtin_amdgcn_mfma_f32_16x16x32_bf16(af, bv, acc[j], 0, 0, 0);
      }
    }
  };

  STG(0, 0);
  __syncthreads();
#pragma unroll 1
  for (int st = 0; st < 8; ++st) {
    if (st < 7) STG(st + 1, (st + 1) & 1);
    COMPUTE(st & 1);
    __syncthreads();
  }

  float* outp = KTVp + ((size_t)bh * 8 + chunk) * 4096;
#pragma unroll
  for (int j = 0; j < 4; ++j)
#pragma unroll
    for (int r = 0; r < 4; ++r)
      outp[(wave * 16 + kg * 4 + r) * 64 + j * 16 + lr] = acc[j][r];
  if (lr == 0) {
#pragma unroll
    for (int r = 0; r < 4; ++r)
      ksump[((size_t)bh * 8 + chunk) * 64 + wave * 16 + kg * 4 + r] = acc_ks[r];
  }
}

// ---------------------------------------------------------------- kernel 3: reduce partials -> KTV^T bf16 + ksum fp32
__global__ __launch_bounds__(256) void ktv_red_k(const float* __restrict__ KTVp,
                                                 const float* __restrict__ ksump,
                                                 ushort* __restrict__ KTVTb,
                                                 float* __restrict__ ksum) {
  const int bh = blockIdx.x, t = threadIdx.x;
  for (int li = t; li < 4096; li += 256) {   // li = v*64 + a
    const int v = li >> 6, a = li & 63;
    float s = 0.f;
    for (int c = 0; c < 8; c++) s += KTVp[((size_t)bh * 8 + c) * 4096 + a * 64 + v];
    KTVTb[(size_t)bh * 4096 + li] = f2bf(s);
  }
  if (t < 64) {
    float s = 0.f;
    for (int c = 0; c < 8; c++) s += ksump[((size_t)bh * 8 + c) * 64 + t];
    ksum[bh * 64 + t] = s;
  }
}

// ---------------------------------------------------------------- kernel 4: Q GEMM + fused phi + numerator/denominator/output
__global__ __launch_bounds__(512, 2) void gemm_q_k(const ushort* __restrict__ xb,
                                                   const ushort* __restrict__ W3b,
                                                   const float* __restrict__ bias3,
                                                   const ushort* __restrict__ KTVTb,
                                                   const float* __restrict__ ksum,
                                                   float* __restrict__ out) {
  __shared__ __align__(16) ushort As[2 * 16384];
  __shared__ __align__(16) ushort Bs[2 * 16384];
  const int t = threadIdx.x, wave = t >> 6, lane = t & 63;
  const int lr = lane & 15, kg = lane >> 4;
  const int wr = wave >> 2, wc = wave & 3;

  // XCD-bijective swizzle: 512 = 8 * 64; per XCD 16 m x 4 n, n fastest.
  const int flat = blockIdx.x;
  const int swz  = (flat & 7) * 64 + (flat >> 3);
  const int n0 = (swz % 4) * 256;
  const int m0 = (swz / 4) * 256;

  const int srow8 = lane >> 3;
  const int sg    = (lane & 7) ^ ((lane >> 3) & 7);

  auto STAGE = [&](int tile, int buf) {
    const int kt = tile * 64;
#pragma unroll
    for (int i = 0; i < 4; ++i) {
      const int r0 = (wave * 4 + i) * 8;
      gld_lds16(xb  + (size_t)(m0 + r0 + srow8) * 1024 + kt + sg * 8,
                As + buf * 16384 + (wave * 4 + i) * 512);
      gld_lds16(W3b + (size_t)(n0 + r0 + srow8) * 1024 + kt + sg * 8,
                Bs + buf * 16384 + (wave * 4 + i) * 512);
    }
  };

  f32x4 acc[8][4];
#pragma unroll
  for (int f = 0; f < 8; f++)
#pragma unroll
    for (int j = 0; j < 4; j++) acc[f][j] = (f32x4){0.f, 0.f, 0.f, 0.f};

  auto COMPUTE = [&](int buf) {
    const ushort* Ab = As + buf * 16384;
    const ushort* Bb = Bs + buf * 16384;
#pragma unroll
    for (int kk = 0; kk < 2; ++kk) {
      const int cp = ((kk * 4 + kg) ^ (lr & 7)) * 8;
      bf16x8 af[8], bfr[4];
#pragma unroll
      for (int f = 0; f < 8; f++)
        af[f] = *reinterpret_cast<const bf16x8*>(Ab + (wr * 128 + f * 16 + lr) * 64 + cp);
#pragma unroll
      for (int j = 0; j < 4; j++)
        bfr[j] = *reinterpret_cast<const bf16x8*>(Bb + (wc * 64 + j * 16 + lr) * 64 + cp);
      __builtin_amdgcn_s_setprio(1);
#pragma unroll
      for (int f = 0; f < 8; f++)
#pragma unroll
        for (int j = 0; j < 4; j++)
          acc[f][j] = __builtin_amdgcn_mfma_f32_16x16x32_bf16(af[f], bfr[j], acc[f][j], 0, 0, 0);
      __builtin_amdgcn_s_setprio(0);
    }
  };

  STAGE(0, 0);
#pragma unroll 1
  for (int tt = 0; tt < 7; ++tt) {
    STAGE(tt * 2 + 1, 1);
    asm volatile("s_waitcnt vmcnt(8)" ::: "memory");
    __builtin_amdgcn_s_barrier();
    COMPUTE(0);
    asm volatile("" ::: "memory");
    __builtin_amdgcn_s_barrier();
    STAGE(tt * 2 + 2, 0);
    asm volatile("s_waitcnt vmcnt(8)" ::: "memory");
    __builtin_amdgcn_s_barrier();
    COMPUTE(1);
    asm volatile("" ::: "memory");
    __builtin_amdgcn_s_barrier();
  }
  STAGE(15, 1);
  asm volatile("s_waitcnt vmcnt(8)" ::: "memory");
  __builtin_amdgcn_s_barrier();
  COMPUTE(0);
  asm volatile("" ::: "memory");
  __builtin_amdgcn_s_barrier();
  asm volatile("s_waitcnt vmcnt(0)" ::: "memory");
  __builtin_amdgcn_s_barrier();
  COMPUTE(1);

  // ---- fused epilogue (unchanged from round 14) ----
  const int n0w = n0 + wc * 64;
  const int h   = n0w >> 6;              // head 0..15
  const int bq  = m0 >> 13;
  const int bh  = bq * Hc + h;
  const int s_base = (m0 & 8191) + wr * 128;
  float bias[4];
#pragma unroll
  for (int j = 0; j < 4; j++) bias[j] = bias3[n0w + j * 16 + lr];

  __syncthreads();   // all staging-LDS reads complete -> reuse as transpose scratch
  ushort* ep = (wave < 4) ? (As + wave * 8192) : (Bs + (wave - 4) * 8192);  // [128][64]

  // 1) phi extract + transpose-store (D-layout -> row-major [s][a], granule-XOR swizzled)
#pragma unroll
  for (int f = 0; f < 8; f++)
#pragma unroll
    for (int j = 0; j < 4; j++) {
      const int g = j * 2 + (lr >> 3);      // col granule (8 elems)
      const int cl = lr & 7;
#pragma unroll
      for (int r = 0; r < 4; r++) {
        const int row = f * 16 + kg * 4 + r;
        float p = acc[f][j][r] + bias[j];
        ep[row * 64 + ((g ^ (row & 7)) << 3) + cl] = f2bf(sqrtf(1.f + p * p));
      }
    }

  // 2) persistent operands: KTV^T B-frags (L2-hot) and ksum slices
  bf16x8 bfr[4][2];
#pragma unroll
  for (int j = 0; j < 4; j++)
#pragma unroll
    for (int ks = 0; ks < 2; ks++)
      bfr[j][ks] = *reinterpret_cast<const bf16x8*>(
          &KTVTb[(size_t)bh * 4096 + (j * 16 + lr) * 64 + ks * 32 + kg * 8]);
  float ksc[2][8];
#pragma unroll
  for (int ks = 0; ks < 2; ks++) {
    float4 v0 = *reinterpret_cast<const float4*>(&ksum[bh * 64 + ks * 32 + kg * 8]);
    float4 v1 = *reinterpret_cast<const float4*>(&ksum[bh * 64 + ks * 32 + kg * 8 + 4]);
    ksc[ks][0] = v0.x; ksc[ks][1] = v0.y; ksc[ks][2] = v0.z; ksc[ks][3] = v0.w;
    ksc[ks][4] = v1.x; ksc[ks][5] = v1.y; ksc[ks][6] = v1.z; ksc[ks][7] = v1.w;
  }

  // 3) per f-block: A-frag readback, denominator, numerator MFMA, write out
#pragma unroll 1
  for (int f = 0; f < 8; f++) {
    bf16x8 af[2];
#pragma unroll
    for (int ks = 0; ks < 2; ks++)
      af[ks] = *reinterpret_cast<const bf16x8*>(
          &ep[(f * 16 + lr) * 64 + (((ks * 4 + kg) ^ (lr & 7)) << 3)]);
    float d = 0.f;
#pragma unroll
    for (int ks = 0; ks < 2; ks++)
#pragma unroll
      for (int e = 0; e < 8; e++) d += (float)af[ks][e] * ksc[ks][e];
    d += __shfl_xor(d, 16, 64);
    d += __shfl_xor(d, 32, 64);
    float den[4];
#pragma unroll
    for (int r = 0; r < 4; r++) den[r] = __shfl(d, kg * 4 + r, 64) + EPSc;
    f32x4 nacc[4];
#pragma unroll
    for (int j = 0; j < 4; j++) nacc[j] = (f32x4){0.f, 0.f, 0.f, 0.f};
#pragma unroll
    for (int ks = 0; ks < 2; ks++)
#pragma unroll
      for (int j = 0; j < 4; j++)
        nacc[j] = __builtin_amdgcn_mfma_f32_16x16x32_bf16(af[ks], bfr[j][ks], nacc[j], 0, 0, 0);
#pragma unroll
    for (int j = 0; j < 4; j++)
#pragma unroll
      for (int r = 0; r < 4; r++) {
        const int s = s_base + f * 16 + kg * 4 + r;
        out[((size_t)bq * Sc + s) * 1024 + h * 64 + j * 16 + lr] = nacc[j][r] / den[r];
      }
  }
}

// ---------------------------------------------------------------- launch
extern "C" void kernel_launch(void* const* d_in, const int* in_sizes, int n_in,
                              void* d_out, int out_size, void* d_ws, size_t ws_size,
                              hipStream_t stream) {
  const float* x     = (const float*)d_in[0];
  const float* W_qkv = (const float*)d_in[1];
  const float* b_qkv = (const float*)d_in[2];
  const float* W_p   = (const float*)d_in[3];
  const float* b_p   = (const float*)d_in[4];
  float* out = (float*)d_out;

  size_t off = 0;
  auto carve = [&](size_t bytes) -> void* {
    void* p = (char*)d_ws + off;
    off += (bytes + 255) & ~(size_t)255;
    return p;
  };
  const size_t headElems = (size_t)BHc * Sc * 64;           // 33,554,432
  ushort* xb    = (ushort*)carve((size_t)Mc * Dc * 2);      // 64 MB
  ushort* KTb   = (ushort*)carve(headElems * 2);            // phiK  [B,H,64,S]
  ushort* VTb   = (ushort*)carve(headElems * 2);            // V     [B,H,64,S]
  ushort* W3b   = (ushort*)carve((size_t)N3c * Dc * 2);
  float*  bias3 = (float*)carve((size_t)N3c * 4);
  float*  KTVp  = (float*)carve((size_t)BHc * 8 * 4096 * 4);
  float*  ksmp  = (float*)carve((size_t)BHc * 8 * 64 * 4);
  ushort* KTVTb = (ushort*)carve((size_t)BHc * 4096 * 2);   // KTV^T bf16 [bh][v][a]
  float*  ksum  = (float*)carve((size_t)BHc * 64 * 4);
  (void)ws_size; (void)n_in; (void)in_sizes; (void)out_size;

  prep_k<<<2096, 256, 0, stream>>>(x, xb, W_qkv, W_p, b_qkv, b_p, W3b, bias3);
  gemm_kv_k<<<(Mc / 256) * (2048 / 256), 512, 0, stream>>>(xb, W3b, bias3, KTb, VTb);
  ktv_part_k<<<dim3(8, BHc), 256, 0, stream>>>(KTb, VTb, KTVp, ksmp);
  ktv_red_k<<<BHc, 256, 0, stream>>>(KTVp, ksmp, KTVTb, ksum);
  gemm_q_k<<<(Mc / 256) * (1024 / 256), 512, 0, stream>>>(xb, W3b, bias3, KTVTb, ksum, out);
}

// Round 16
// 383.080 us; speedup vs baseline: 1.0172x; 1.0172x over previous
//
#include <hip/hip_runtime.h>
#include <hip/hip_bf16.h>
#include <cstdint>

// Problem constants
static constexpr int Bc  = 4;
static constexpr int Sc  = 8192;
static constexpr int Dc  = 1024;
static constexpr int Hc  = 16;
static constexpr int BHc = Bc * Hc;   // 64
static constexpr int Mc  = Bc * Sc;   // 32768
static constexpr int N3c = 3 * Dc;    // 3072
static constexpr float EPSc = 1e-6f;

using bf16x8 = __attribute__((ext_vector_type(8))) __bf16;
using f32x4  = __attribute__((ext_vector_type(4))) float;

__device__ __forceinline__ ushort f2bf(float f) {
  union { float f; uint32_t u; } v; v.f = f;
  uint32_t u = v.u;
  return (ushort)((u + 0x7fffu + ((u >> 16) & 1u)) >> 16);  // RNE
}
__device__ __forceinline__ float bf2f(ushort h) {
  union { uint32_t u; float f; } v; v.u = ((uint32_t)h) << 16;
  return v.f;
}

typedef const __attribute__((address_space(1))) unsigned int* gas_u32p;
typedef __attribute__((address_space(3))) unsigned int* las_u32p;
__device__ __forceinline__ void gld_lds16(const void* g, void* l) {
  __builtin_amdgcn_global_load_lds((gas_u32p)g, (las_u32p)l, 16, 0, 0);
}

// ---------------------------------------------------------------- kernel 0: fused prep
// blocks 0..2047: fp32->bf16 convert of x.  blocks 2048..2095: weight fold
// (rows 0..1023: W_p@W_Q, bias=W_p b_Q+b_p; 1024..2047: W_p@W_K; 2048..3071: W_V, b_V).
__global__ __launch_bounds__(256) void prep_k(const float* __restrict__ x,
                                              ushort* __restrict__ xb,
                                              const float* __restrict__ Wq,
                                              const float* __restrict__ Wp,
                                              const float* __restrict__ bq,
                                              const float* __restrict__ bp,
                                              ushort* __restrict__ W3b,
                                              float* __restrict__ bias3) {
  const int t = threadIdx.x;
  if (blockIdx.x < 2048) {
    const int n4 = Mc * Dc / 4;
    for (int i = blockIdx.x * 256 + t; i < n4; i += 2048 * 256) {
      float4 v = reinterpret_cast<const float4*>(x)[i];
      ushort4 o; o.x = f2bf(v.x); o.y = f2bf(v.y); o.z = f2bf(v.z); o.w = f2bf(v.w);
      reinterpret_cast<ushort4*>(xb)[i] = o;
    }
    return;
  }
  const int bx = blockIdx.x - 2048;   // 0..47
  const int p = bx >> 4, h = bx & 15;
  if (p == 2) {
    const int base = 2048 + h * 64;
    for (int li = t; li < 64 * 256; li += 256) {
      int r = li >> 8, c4 = (li & 255) * 4;
      float4 v = *reinterpret_cast<const float4*>(&Wq[(size_t)(base + r) * 1024 + c4]);
      ushort4 o; o.x = f2bf(v.x); o.y = f2bf(v.y); o.z = f2bf(v.z); o.w = f2bf(v.w);
      *reinterpret_cast<ushort4*>(&W3b[(size_t)(base + r) * 1024 + c4]) = o;
    }
    if (t < 64) bias3[base + t] = bq[base + t];
    return;
  }
  __shared__ ushort Ws[64 * 64];    // [a][hd]
  __shared__ ushort Tq[256 * 64];   // [d][hd]
  const int rbase = p * 1024 + h * 64;
  for (int li = t; li < 64 * 16; li += 256) {
    int a = li >> 4, h4 = (li & 15) * 4;
    float4 v = *reinterpret_cast<const float4*>(&Wp[a * 64 + h4]);
    ushort4 o; o.x = f2bf(v.x); o.y = f2bf(v.y); o.z = f2bf(v.z); o.w = f2bf(v.w);
    *reinterpret_cast<ushort4*>(&Ws[a * 64 + h4]) = o;
  }
  if (t < 64) {
    float s = bp[t];
    for (int hd = 0; hd < 64; ++hd) s += Wp[t * 64 + hd] * bq[rbase + hd];
    bias3[rbase + t] = s;
  }
  const int w = t >> 6, lane = t & 63, lr = lane & 15, kg = lane >> 4;
  for (int dt = 0; dt < 4; ++dt) {
    __syncthreads();
    for (int li = t; li < 64 * 64; li += 256) {
      int hd = li >> 6, d4 = (li & 63) * 4;
      float4 v = *reinterpret_cast<const float4*>(&Wq[(size_t)(rbase + hd) * 1024 + dt * 256 + d4]);
      Tq[(d4 + 0) * 64 + hd] = f2bf(v.x);
      Tq[(d4 + 1) * 64 + hd] = f2bf(v.y);
      Tq[(d4 + 2) * 64 + hd] = f2bf(v.z);
      Tq[(d4 + 3) * 64 + hd] = f2bf(v.w);
    }
    __syncthreads();
    f32x4 acc[4][4];
#pragma unroll
    for (int i = 0; i < 4; i++)
#pragma unroll
      for (int j = 0; j < 4; j++) acc[i][j] = (f32x4){0.f, 0.f, 0.f, 0.f};
#pragma unroll
    for (int kk = 0; kk < 2; ++kk) {
      bf16x8 af[4], bfr[4];
#pragma unroll
      for (int i = 0; i < 4; i++)
        af[i] = *reinterpret_cast<const bf16x8*>(&Ws[(i * 16 + lr) * 64 + kk * 32 + kg * 8]);
#pragma unroll
      for (int j = 0; j < 4; j++)
        bfr[j] = *reinterpret_cast<const bf16x8*>(&Tq[(w * 64 + j * 16 + lr) * 64 + kk * 32 + kg * 8]);
#pragma unroll
      for (int i = 0; i < 4; i++)
#pragma unroll
        for (int j = 0; j < 4; j++)
          acc[i][j] = __builtin_amdgcn_mfma_f32_16x16x32_bf16(af[i], bfr[j], acc[i][j], 0, 0, 0);
    }
#pragma unroll
    for (int i = 0; i < 4; i++)
#pragma unroll
      for (int j = 0; j < 4; j++)
#pragma unroll
        for (int r = 0; r < 4; r++)
          W3b[(size_t)(rbase + i * 16 + kg * 4 + r) * 1024 + dt * 256 + w * 64 + j * 16 + lr] =
              f2bf(acc[i][j][r]);
  }
}

// ---------------------------------------------------------------- kernel 1: K/V GEMM + fused phi(K)
// Champion structure (256x256, BK=32, 8 waves, 4-buf ring, depth-3, vmcnt(8), XOR swizzle).
// N-range [1024, 3072): parts 1 (phiK, T-layout) and 2 (V, T-layout) only.
__global__ __launch_bounds__(512, 2) void gemm_kv_k(const ushort* __restrict__ xb,
                                                    const ushort* __restrict__ W3b,
                                                    const float* __restrict__ bias3,
                                                    ushort* __restrict__ KTb,
                                                    ushort* __restrict__ VTb) {
  __shared__ __align__(16) ushort As[4 * 8192];
  __shared__ __align__(16) ushort Bs[4 * 8192];
  const int t = threadIdx.x, wave = t >> 6, lane = t & 63;
  const int lr = lane & 15, kg = lane >> 4;
  const int wr = wave >> 2, wc = wave & 3;

  // XCD-bijective swizzle: 1024 = 8 * 128; per XCD 16 m x 8 n, n fastest.
  const int flat = blockIdx.x;
  const int swz  = (flat & 7) * 128 + (flat >> 3);
  const int n0 = 1024 + (swz % 8) * 256;
  const int m0 = (swz / 8) * 256;

  const int srow = t >> 2;
  const int sg   = (t & 3) ^ ((t >> 3) & 3);
  const int swb  = wave * 512;

  auto STAGE = [&](int tile, int buf) {
    const int kt = tile * 32;
#pragma unroll
    for (int is = 0; is < 2; ++is) {
      gld_lds16(xb  + (size_t)(m0 + is * 128 + srow) * 1024 + kt + sg * 8,
                As + buf * 8192 + is * 4096 + swb);
      gld_lds16(W3b + (size_t)(n0 + is * 128 + srow) * 1024 + kt + sg * 8,
                Bs + buf * 8192 + is * 4096 + swb);
    }
  };

  f32x4 acc[8][4];
#pragma unroll
  for (int f = 0; f < 8; f++)
#pragma unroll
    for (int j = 0; j < 4; j++) acc[f][j] = (f32x4){0.f, 0.f, 0.f, 0.f};

  const int cp = (kg ^ ((lr >> 1) & 3)) * 8;
  const ushort* Ard = As + (wr * 128 + lr) * 32 + cp;
  const ushort* Brd = Bs + (wc * 64 + lr) * 32 + cp;

  auto COMPUTE = [&](int buf) {
    bf16x8 af[8], bfr[4];
    const ushort* Ab = Ard + buf * 8192;
    const ushort* Bb = Brd + buf * 8192;
#pragma unroll
    for (int f = 0; f < 8; f++) af[f] = *reinterpret_cast<const bf16x8*>(Ab + f * 512);
#pragma unroll
    for (int j = 0; j < 4; j++) bfr[j] = *reinterpret_cast<const bf16x8*>(Bb + j * 512);
    __builtin_amdgcn_s_setprio(1);
#pragma unroll
    for (int f = 0; f < 8; f++)
#pragma unroll
      for (int j = 0; j < 4; j++)
        acc[f][j] = __builtin_amdgcn_mfma_f32_16x16x32_bf16(af[f], bfr[j], acc[f][j], 0, 0, 0);
    __builtin_amdgcn_s_setprio(0);
  };

  STAGE(0, 0);
  STAGE(1, 1);
  STAGE(2, 2);
  asm volatile("s_waitcnt vmcnt(8)" ::: "memory");
  __builtin_amdgcn_s_barrier();

#pragma unroll 1
  for (int i = 0; i < 7; ++i) {
    const int tb = i * 4;
#pragma unroll
    for (int j = 0; j < 4; ++j) {
      STAGE(tb + j + 3, (j + 3) & 3);
      COMPUTE(j);
      asm volatile("s_waitcnt vmcnt(8)" ::: "memory");
      __builtin_amdgcn_s_barrier();
    }
  }
  STAGE(31, 3);
  COMPUTE(0);
  asm volatile("s_waitcnt vmcnt(8)" ::: "memory");
  __builtin_amdgcn_s_barrier();
  COMPUTE(1);
  asm volatile("s_waitcnt vmcnt(4)" ::: "memory");
  __builtin_amdgcn_s_barrier();
  COMPUTE(2);
  asm volatile("s_waitcnt vmcnt(0)" ::: "memory");
  __builtin_amdgcn_s_barrier();
  COMPUTE(3);

  // epilogue: part 1 = phiK (T), part 2 = V (T)
  const int n0w  = n0 + wc * 64;
  const int part = n0w >> 10;           // 1 or 2
  const int h    = (n0w & 1023) >> 6;
  const int bq   = m0 >> 13;
  const int s_base = (m0 & 8191) + wr * 128;
  float bias[4];
#pragma unroll
  for (int j = 0; j < 4; j++) bias[j] = bias3[n0w + j * 16 + lr];

  ushort* dst = ((part == 1) ? KTb : VTb) + ((size_t)(bq * Hc + h)) * 64 * Sc;
#pragma unroll
  for (int f = 0; f < 8; f++) {
    const int s = s_base + f * 16 + kg * 4;
#pragma unroll
    for (int j = 0; j < 4; j++) {
      ushort4 o;
      if (part == 1) {
#pragma unroll
        for (int r = 0; r < 4; r++) {
          float p = acc[f][j][r] + bias[j];
          (&o.x)[r] = f2bf(sqrtf(1.f + p * p));
        }
      } else {
#pragma unroll
        for (int r = 0; r < 4; r++) (&o.x)[r] = f2bf(acc[f][j][r] + bias[j]);
      }
      *reinterpret_cast<ushort4*>(&dst[(size_t)(j * 16 + lr) * Sc + s]) = o;
    }
  }
}

// ---------------------------------------------------------------- kernel 2: KTV + ksum partials (T-layout inputs)
__global__ __launch_bounds__(256, 2) void ktv_part_k(const ushort* __restrict__ KT,
                                                     const ushort* __restrict__ VT,
                                                     float* __restrict__ KTVp,
                                                     float* __restrict__ ksump) {
  __shared__ __align__(16) ushort Ks[2 * 8192];   // 2 bufs x [64 a][128 s]
  __shared__ __align__(16) ushort Vs[2 * 8192];
  const int t = threadIdx.x, chunk = blockIdx.x, bh = blockIdx.y;
  const int wave = t >> 6, lane = t & 63, lr = lane & 15, kg = lane >> 4;
  const size_t hb = (size_t)bh * 64 * Sc;
  const int s0 = chunk * 1024;

  f32x4 acc[4];
  f32x4 acc_ks;
#pragma unroll
  for (int j = 0; j < 4; j++) acc[j] = (f32x4){0.f, 0.f, 0.f, 0.f};
  acc_ks = (f32x4){0.f, 0.f, 0.f, 0.f};

  bf16x8 ones;
#pragma unroll
  for (int e = 0; e < 8; e++) ones[e] = (__bf16)1.0f;

  const int srl = t >> 4;
  const int scc = (t & 15) ^ ((t >> 4) & 7);
  const int wb  = (t >> 6) * 512;

  auto STG = [&](int st, int buf) {
    const int sb = s0 + st * 128;
#pragma unroll
    for (int is = 0; is < 4; ++is) {
      const int row = is * 16 + srl;
      gld_lds16(KT + hb + (size_t)row * Sc + sb + scc * 8, Ks + buf * 8192 + is * 2048 + wb);
      gld_lds16(VT + hb + (size_t)row * Sc + sb + scc * 8, Vs + buf * 8192 + is * 2048 + wb);
    }
  };

  auto COMPUTE = [&](int buf) {
    const ushort* Kb = Ks + buf * 8192;
    const ushort* Vb = Vs + buf * 8192;
#pragma unroll
    for (int ks4 = 0; ks4 < 4; ++ks4) {
      const int pos = ((ks4 * 4 + kg) ^ (lr & 7)) * 8;
      bf16x8 af = *reinterpret_cast<const bf16x8*>(Kb + (wave * 16 + lr) * 128 + pos);
      acc_ks = __builtin_amdgcn_mfma_f32_16x16x32_bf16(af, ones, acc_ks, 0, 0, 0);
#pragma unroll
      for (int j = 0; j < 4; ++j) {
        bf16x8 bv = *reinterpret_cast<const bf16x8*>(Vb + (j * 16 + lr) * 128 + pos);
        acc[j] = __builtin_amdgcn_mfma_f32_16x16x32_bf16(af, bv, acc[j], 0, 0, 0);
      }
    }
  };

  STG(0, 0);
  __syncthreads();
#pragma unroll 1
  for (int st = 0; st < 8; ++st) {
    if (st < 7) STG(st + 1, (st + 1) & 1);
    COMPUTE(st & 1);
    __syncthreads();
  }

  float* outp = KTVp + ((size_t)bh * 8 + chunk) * 4096;
#pragma unroll
  for (int j = 0; j < 4; ++j)
#pragma unroll
    for (int r = 0; r < 4; ++r)
      outp[(wave * 16 + kg * 4 + r) * 64 + j * 16 + lr] = acc[j][r];
  if (lr == 0) {
#pragma unroll
    for (int r = 0; r < 4; ++r)
      ksump[((size_t)bh * 8 + chunk) * 64 + wave * 16 + kg * 4 + r] = acc_ks[r];
  }
}

// ---------------------------------------------------------------- kernel 3: reduce partials -> KTV^T bf16 + ksum fp32
__global__ __launch_bounds__(256) void ktv_red_k(const float* __restrict__ KTVp,
                                                 const float* __restrict__ ksump,
                                                 ushort* __restrict__ KTVTb,
                                                 float* __restrict__ ksum) {
  const int bh = blockIdx.x, t = threadIdx.x;
  for (int li = t; li < 4096; li += 256) {   // li = v*64 + a
    const int v = li >> 6, a = li & 63;
    float s = 0.f;
    for (int c = 0; c < 8; c++) s += KTVp[((size_t)bh * 8 + c) * 4096 + a * 64 + v];
    KTVTb[(size_t)bh * 4096 + li] = f2bf(s);
  }
  if (t < 64) {
    float s = 0.f;
    for (int c = 0; c < 8; c++) s += ksump[((size_t)bh * 8 + c) * 64 + t];
    ksum[bh * 64 + t] = s;
  }
}

// ---------------------------------------------------------------- kernel 4: Q GEMM + fused phi + numerator/denominator/output
// Champion main loop over N-range [0,1024). Epilogue keeps phiQ in registers:
// transpose D-layout -> A-frag layout through the dead staging LDS (per-wave 16 KB,
// XOR-swizzled), then numerator = phiQ x KTV^T via MFMA, denominator via per-lane dot
// + shfl reduce, fp32 out written directly.
__global__ __launch_bounds__(512, 2) void gemm_q_k(const ushort* __restrict__ xb,
                                                   const ushort* __restrict__ W3b,
                                                   const float* __restrict__ bias3,
                                                   const ushort* __restrict__ KTVTb,
                                                   const float* __restrict__ ksum,
                                                   float* __restrict__ out) {
  __shared__ __align__(16) ushort As[4 * 8192];
  __shared__ __align__(16) ushort Bs[4 * 8192];
  const int t = threadIdx.x, wave = t >> 6, lane = t & 63;
  const int lr = lane & 15, kg = lane >> 4;
  const int wr = wave >> 2, wc = wave & 3;

  // XCD-bijective swizzle: 512 = 8 * 64; per XCD 16 m x 4 n, n fastest.
  const int flat = blockIdx.x;
  const int swz  = (flat & 7) * 64 + (flat >> 3);
  const int n0 = (swz % 4) * 256;
  const int m0 = (swz / 4) * 256;

  const int srow = t >> 2;
  const int sg   = (t & 3) ^ ((t >> 3) & 3);
  const int swb  = wave * 512;

  auto STAGE = [&](int tile, int buf) {
    const int kt = tile * 32;
#pragma unroll
    for (int is = 0; is < 2; ++is) {
      gld_lds16(xb  + (size_t)(m0 + is * 128 + srow) * 1024 + kt + sg * 8,
                As + buf * 8192 + is * 4096 + swb);
      gld_lds16(W3b + (size_t)(n0 + is * 128 + srow) * 1024 + kt + sg * 8,
                Bs + buf * 8192 + is * 4096 + swb);
    }
  };

  f32x4 acc[8][4];
#pragma unroll
  for (int f = 0; f < 8; f++)
#pragma unroll
    for (int j = 0; j < 4; j++) acc[f][j] = (f32x4){0.f, 0.f, 0.f, 0.f};

  const int cp = (kg ^ ((lr >> 1) & 3)) * 8;
  const ushort* Ard = As + (wr * 128 + lr) * 32 + cp;
  const ushort* Brd = Bs + (wc * 64 + lr) * 32 + cp;

  auto COMPUTE = [&](int buf) {
    bf16x8 af[8], bfr[4];
    const ushort* Ab = Ard + buf * 8192;
    const ushort* Bb = Brd + buf * 8192;
#pragma unroll
    for (int f = 0; f < 8; f++) af[f] = *reinterpret_cast<const bf16x8*>(Ab + f * 512);
#pragma unroll
    for (int j = 0; j < 4; j++) bfr[j] = *reinterpret_cast<const bf16x8*>(Bb + j * 512);
    __builtin_amdgcn_s_setprio(1);
#pragma unroll
    for (int f = 0; f < 8; f++)
#pragma unroll
      for (int j = 0; j < 4; j++)
        acc[f][j] = __builtin_amdgcn_mfma_f32_16x16x32_bf16(af[f], bfr[j], acc[f][j], 0, 0, 0);
    __builtin_amdgcn_s_setprio(0);
  };

  STAGE(0, 0);
  STAGE(1, 1);
  STAGE(2, 2);
  asm volatile("s_waitcnt vmcnt(8)" ::: "memory");
  __builtin_amdgcn_s_barrier();

#pragma unroll 1
  for (int i = 0; i < 7; ++i) {
    const int tb = i * 4;
#pragma unroll
    for (int j = 0; j < 4; ++j) {
      STAGE(tb + j + 3, (j + 3) & 3);
      COMPUTE(j);
      asm volatile("s_waitcnt vmcnt(8)" ::: "memory");
      __builtin_amdgcn_s_barrier();
    }
  }
  STAGE(31, 3);
  COMPUTE(0);
  asm volatile("s_waitcnt vmcnt(8)" ::: "memory");
  __builtin_amdgcn_s_barrier();
  COMPUTE(1);
  asm volatile("s_waitcnt vmcnt(4)" ::: "memory");
  __builtin_amdgcn_s_barrier();
  COMPUTE(2);
  asm volatile("s_waitcnt vmcnt(0)" ::: "memory");
  __builtin_amdgcn_s_barrier();
  COMPUTE(3);

  // ---- fused epilogue ----
  const int n0w = n0 + wc * 64;
  const int h   = n0w >> 6;              // head 0..15
  const int bq  = m0 >> 13;
  const int bh  = bq * Hc + h;
  const int s_base = (m0 & 8191) + wr * 128;
  float bias[4];
#pragma unroll
  for (int j = 0; j < 4; j++) bias[j] = bias3[n0w + j * 16 + lr];

  __syncthreads();   // all staging-LDS reads complete -> reuse as transpose scratch
  ushort* ep = (wave < 4) ? (As + wave * 8192) : (Bs + (wave - 4) * 8192);  // [128][64]

  // 1) phi extract + transpose-store (D-layout -> row-major [s][a], granule-XOR swizzled)
#pragma unroll
  for (int f = 0; f < 8; f++)
#pragma unroll
    for (int j = 0; j < 4; j++) {
      const int g = j * 2 + (lr >> 3);      // col granule (8 elems)
      const int cl = lr & 7;
#pragma unroll
      for (int r = 0; r < 4; r++) {
        const int row = f * 16 + kg * 4 + r;
        float p = acc[f][j][r] + bias[j];
        ep[row * 64 + ((g ^ (row & 7)) << 3) + cl] = f2bf(sqrtf(1.f + p * p));
      }
    }

  // 2) persistent operands: KTV^T B-frags (L2-hot) and ksum slices
  bf16x8 bfr[4][2];
#pragma unroll
  for (int j = 0; j < 4; j++)
#pragma unroll
    for (int ks = 0; ks < 2; ks++)
      bfr[j][ks] = *reinterpret_cast<const bf16x8*>(
          &KTVTb[(size_t)bh * 4096 + (j * 16 + lr) * 64 + ks * 32 + kg * 8]);
  float ksc[2][8];
#pragma unroll
  for (int ks = 0; ks < 2; ks++) {
    float4 v0 = *reinterpret_cast<const float4*>(&ksum[bh * 64 + ks * 32 + kg * 8]);
    float4 v1 = *reinterpret_cast<const float4*>(&ksum[bh * 64 + ks * 32 + kg * 8 + 4]);
    ksc[ks][0] = v0.x; ksc[ks][1] = v0.y; ksc[ks][2] = v0.z; ksc[ks][3] = v0.w;
    ksc[ks][4] = v1.x; ksc[ks][5] = v1.y; ksc[ks][6] = v1.z; ksc[ks][7] = v1.w;
  }

  // 3) per f-block: A-frag readback, denominator, numerator MFMA, write out
#pragma unroll 1
  for (int f = 0; f < 8; f++) {
    bf16x8 af[2];
#pragma unroll
    for (int ks = 0; ks < 2; ks++)
      af[ks] = *reinterpret_cast<const bf16x8*>(
          &ep[(f * 16 + lr) * 64 + (((ks * 4 + kg) ^ (lr & 7)) << 3)]);
    float d = 0.f;
#pragma unroll
    for (int ks = 0; ks < 2; ks++)
#pragma unroll
      for (int e = 0; e < 8; e++) d += (float)af[ks][e] * ksc[ks][e];
    d += __shfl_xor(d, 16, 64);
    d += __shfl_xor(d, 32, 64);
    float den[4];
#pragma unroll
    for (int r = 0; r < 4; r++) den[r] = __shfl(d, kg * 4 + r, 64) + EPSc;
    f32x4 nacc[4];
#pragma unroll
    for (int j = 0; j < 4; j++) nacc[j] = (f32x4){0.f, 0.f, 0.f, 0.f};
#pragma unroll
    for (int ks = 0; ks < 2; ks++)
#pragma unroll
      for (int j = 0; j < 4; j++)
        nacc[j] = __builtin_amdgcn_mfma_f32_16x16x32_bf16(af[ks], bfr[j][ks], nacc[j], 0, 0, 0);
#pragma unroll
    for (int j = 0; j < 4; j++)
#pragma unroll
      for (int r = 0; r < 4; r++) {
        const int s = s_base + f * 16 + kg * 4 + r;
        out[((size_t)bq * Sc + s) * 1024 + h * 64 + j * 16 + lr] = nacc[j][r] / den[r];
      }
  }
}

// ---------------------------------------------------------------- launch
extern "C" void kernel_launch(void* const* d_in, const int* in_sizes, int n_in,
                              void* d_out, int out_size, void* d_ws, size_t ws_size,
                              hipStream_t stream) {
  const float* x     = (const float*)d_in[0];
  const float* W_qkv = (const float*)d_in[1];
  const float* b_qkv = (const float*)d_in[2];
  const float* W_p   = (const float*)d_in[3];
  const float* b_p   = (const float*)d_in[4];
  float* out = (float*)d_out;

  size_t off = 0;
  auto carve = [&](size_t bytes) -> void* {
    void* p = (char*)d_ws + off;
    off += (bytes + 255) & ~(size_t)255;
    return p;
  };
  const size_t headElems = (size_t)BHc * Sc * 64;           // 33,554,432
  ushort* xb    = (ushort*)carve((size_t)Mc * Dc * 2);      // 64 MB
  ushort* KTb   = (ushort*)carve(headElems * 2);            // phiK  [B,H,64,S]
  ushort* VTb   = (ushort*)carve(headElems * 2);            // V     [B,H,64,S]
  ushort* W3b   = (ushort*)carve((size_t)N3c * Dc * 2);
  float*  bias3 = (float*)carve((size_t)N3c * 4);
  float*  KTVp  = (float*)carve((size_t)BHc * 8 * 4096 * 4);
  float*  ksmp  = (float*)carve((size_t)BHc * 8 * 64 * 4);
  ushort* KTVTb = (ushort*)carve((size_t)BHc * 4096 * 2);   // KTV^T bf16 [bh][v][a]
  float*  ksum  = (float*)carve((size_t)BHc * 64 * 4);
  (void)ws_size; (void)n_in; (void)in_sizes; (void)out_size;

  prep_k<<<2096, 256, 0, stream>>>(x, xb, W_qkv, W_p, b_qkv, b_p, W3b, bias3);
  gemm_kv_k<<<(Mc / 256) * (2048 / 256), 512, 0, stream>>>(xb, W3b, bias3, KTb, VTb);
  ktv_part_k<<<dim3(8, BHc), 256, 0, stream>>>(KTb, VTb, KTVp, ksmp);
  ktv_red_k<<<BHc, 256, 0, stream>>>(KTVp, ksmp, KTVTb, ksum);
  gemm_q_k<<<(Mc / 256) * (1024 / 256), 512, 0, stream>>>(xb, W3b, bias3, KTVTb, ksum, out);
}